// Round 2
// baseline (36700.714 us; speedup 1.0000x reference)
//
#include <hip/hip_runtime.h>
#include <cstddef>
#include <cstdint>

// ---------------------------------------------------------------------------
// fc1: y[r] = W[r,:] . x + b[r]    (wave per row, 4 rows/block)
// ---------------------------------------------------------------------------
__global__ void fc1_k(const float* __restrict__ W, const float* __restrict__ x,
                      const float* __restrict__ b, float* __restrict__ y,
                      int rows, int cols) {
  int wave = threadIdx.x >> 6, lane = threadIdx.x & 63;
  int r = blockIdx.x * 4 + wave;
  if (r >= rows) return;
  const float* wp = W + (size_t)r * cols;
  float s = 0.f;
  for (int j = lane; j < cols; j += 64) s = fmaf(wp[j], x[j], s);
  for (int o = 32; o; o >>= 1) s += __shfl_down(s, o);
  if (lane == 0) y[r] = s + b[r];
}

// ---------------------------------------------------------------------------
// conv: SAME-pad (1,2) k=4 s=1 cross-correlation, optionally fused with
// nearest-neighbor x2 upsample of the input (UP=1: in is (Cin,Hin,Win),
// logical input is (Cin,2Hin,2Win) == (Cin,OH,OW)).
// One thread per output element.
// ---------------------------------------------------------------------------
template <int UP>
__global__ void conv_k(const float* __restrict__ in, const float* __restrict__ wt,
                       float* __restrict__ out, int Cin, int Cout, int OH, int OW,
                       int Hin, int Win) {
  int idx = blockIdx.x * blockDim.x + threadIdx.x;
  int total = Cout * OH * OW;
  if (idx >= total) return;
  int ox = idx % OW;
  int tt = idx / OW;
  int oy = tt % OH;
  int co = tt / OH;
  const float* wco = wt + (size_t)co * Cin * 16;
  float acc = 0.f;
  for (int ci = 0; ci < Cin; ++ci) {
    const float* ip = in + (size_t)ci * Hin * Win;
    const float* wp = wco + ci * 16;
#pragma unroll
    for (int ky = 0; ky < 4; ++ky) {
      int iy = oy - 1 + ky;
      if ((unsigned)iy >= (unsigned)OH) continue;  // zero pad
      int sy = UP ? (iy >> 1) : iy;
      const float* iprow = ip + sy * Win;
#pragma unroll
      for (int kx = 0; kx < 4; ++kx) {
        int ix = ox - 1 + kx;
        if ((unsigned)ix >= (unsigned)OW) continue;  // zero pad
        int sx = UP ? (ix >> 1) : ix;
        acc = fmaf(iprow[sx], wp[ky * 4 + kx], acc);
      }
    }
  }
  out[idx] = acc;
}

// ---------------------------------------------------------------------------
// BatchNorm training-mode stats (N=1): per-channel mean + rsqrt(var+eps).
// Double accumulation: activations ~1.6e3 with var ~1e3 -> f32 E[x^2]-m^2
// catastrophically cancels.
// ---------------------------------------------------------------------------
__global__ void stats_k(const float* __restrict__ x, float* __restrict__ mean,
                        float* __restrict__ rstd, int HW) {
  int c = blockIdx.x;
  const float* p = x + (size_t)c * HW;
  double s = 0.0, s2 = 0.0;
  for (int i = threadIdx.x; i < HW; i += blockDim.x) {
    float v = p[i];
    s += v;
    s2 += (double)v * (double)v;
  }
  for (int o = 32; o; o >>= 1) {
    s += __shfl_down(s, o);
    s2 += __shfl_down(s2, o);
  }
  __shared__ double sh[2][4];
  int wv = threadIdx.x >> 6, ln = threadIdx.x & 63;
  if (ln == 0) { sh[0][wv] = s; sh[1][wv] = s2; }
  __syncthreads();
  if (threadIdx.x == 0) {
    double S = 0, S2 = 0;
    int nw = blockDim.x >> 6;
    for (int w = 0; w < nw; ++w) { S += sh[0][w]; S2 += sh[1][w]; }
    double m = S / HW;
    double v = S2 / HW - m * m;
    if (v < 0) v = 0;
    mean[c] = (float)m;
    rstd[c] = rsqrtf((float)v + 1e-5f);
  }
}

__global__ void bnrelu_k(float* __restrict__ x, const float* __restrict__ mean,
                         const float* __restrict__ rstd, const float* __restrict__ g,
                         const float* __restrict__ be, int HW, int total) {
  int idx = blockIdx.x * blockDim.x + threadIdx.x;
  if (idx >= total) return;
  int c = idx / HW;
  float v = (x[idx] - mean[c]) * rstd[c] * g[c] + be[c];
  x[idx] = v > 0.f ? v : 0.f;
}

__global__ void tanh_k(float* __restrict__ x, int n) {
  int i = blockIdx.x * blockDim.x + threadIdx.x;
  if (i < n) x[i] = tanhf(x[i]);
}

// ---------------------------------------------------------------------------
// fc2: y[r] = W[r,:] . h + b[r]   (block per row, 256 threads)
// ---------------------------------------------------------------------------
__global__ void fc2_k(const float* __restrict__ W, const float* __restrict__ h,
                      const float* __restrict__ b, float* __restrict__ y, int cols) {
  int r = blockIdx.x;
  const float* wp = W + (size_t)r * cols;
  float s = 0.f;
  for (int j = threadIdx.x; j < cols; j += blockDim.x) s = fmaf(wp[j], h[j], s);
  for (int o = 32; o; o >>= 1) s += __shfl_down(s, o);
  __shared__ float sh[4];
  int wv = threadIdx.x >> 6, ln = threadIdx.x & 63;
  if (ln == 0) sh[wv] = s;
  __syncthreads();
  if (threadIdx.x == 0) y[r] = sh[0] + sh[1] + sh[2] + sh[3] + b[r];
}

// ---------------------------------------------------------------------------
// The serial spiking scan: new[i] = -prev[i] + tanh(sum_j prev[j]*w[j][i]).
// 99800 strictly dependent steps -> single block, latency-optimized:
//   - w columns live in REGISTERS (20 terms per thread, 4 threads/column)
//   - prev double-buffered in LDS, ONE barrier per step
//   - quad reduce via __shfl_xor(1/2) (DPP quad_perm, cheap)
//   - tanh = 1 - 2/(exp(2x)+1), saturates to exactly +/-1 for large |x|
// ---------------------------------------------------------------------------
__global__ __launch_bounds__(320, 1) void scan_k(const float* __restrict__ wmat,
                                                 const float* __restrict__ start,
                                                 float* __restrict__ out, int steps) {
  const int t = threadIdx.x;
  const int i = t >> 2;  // column 0..79 (valid < 69)
  const int k = t & 3;   // quarter of the 69-sum (20 terms each, zero-padded)
  float wr[20];
#pragma unroll
  for (int m = 0; m < 20; ++m) {
    int j = 20 * k + m;
    wr[m] = (i < 69 && j < 69) ? wmat[(size_t)j * 69 + i] : 0.f;
  }
  __shared__ __align__(16) float pbuf[2][80];
  if (t < 80) {
    pbuf[0][t] = (t < 69) ? start[t] : 0.f;
    pbuf[1][t] = 0.f;  // pads [69..79] stay 0 forever
  }
  __syncthreads();
  int p = 0;
  for (int step = 0; step < steps; ++step) {
    const float* pv = pbuf[p];
    const float4* q = reinterpret_cast<const float4*>(pv) + 5 * k;
    float4 q0 = q[0], q1 = q[1], q2 = q[2], q3 = q[3], q4 = q[4];
    float prev_i = pv[i];
    float a0 = q0.x * wr[0];
    float a1 = q0.y * wr[1];
    float a2 = q0.z * wr[2];
    float a3 = q0.w * wr[3];
    a0 = fmaf(q1.x, wr[4], a0);
    a1 = fmaf(q1.y, wr[5], a1);
    a2 = fmaf(q1.z, wr[6], a2);
    a3 = fmaf(q1.w, wr[7], a3);
    a0 = fmaf(q2.x, wr[8], a0);
    a1 = fmaf(q2.y, wr[9], a1);
    a2 = fmaf(q2.z, wr[10], a2);
    a3 = fmaf(q2.w, wr[11], a3);
    a0 = fmaf(q3.x, wr[12], a0);
    a1 = fmaf(q3.y, wr[13], a1);
    a2 = fmaf(q3.z, wr[14], a2);
    a3 = fmaf(q3.w, wr[15], a3);
    a0 = fmaf(q4.x, wr[16], a0);
    a1 = fmaf(q4.y, wr[17], a1);
    a2 = fmaf(q4.z, wr[18], a2);
    a3 = fmaf(q4.w, wr[19], a3);
    float s = (a0 + a1) + (a2 + a3);
    s += __shfl_xor(s, 1);
    s += __shfl_xor(s, 2);
    float e = __expf(2.f * s);
    float th = 1.f - __fdividef(2.f, e + 1.f);
    float nv = th - prev_i;
    if (i < 69) {
      if (k == 0) pbuf[p ^ 1][i] = nv;          // feed recurrence
      else if (k == 1) out[(size_t)step * 69 + i] = nv;  // fire-and-forget
    }
    __syncthreads();
    p ^= 1;
  }
}

// ---------------------------------------------------------------------------
extern "C" void kernel_launch(void* const* d_in, const int* in_sizes, int n_in,
                              void* d_out, int out_size, void* d_ws, size_t ws_size,
                              hipStream_t stream) {
  const float* x    = (const float*)d_in[0];
  const float* strt = (const float*)d_in[1];   // (200,69)
  const float* W_in = (const float*)d_in[2];
  const float* b_in = (const float*)d_in[3];
  const float* w1   = (const float*)d_in[4];
  const float* w2   = (const float*)d_in[5];
  const float* w3   = (const float*)d_in[6];
  const float* w4   = (const float*)d_in[7];
  const float* w5   = (const float*)d_in[8];
  const float* g1   = (const float*)d_in[9];
  const float* be1  = (const float*)d_in[10];
  const float* g2   = (const float*)d_in[11];
  const float* be2  = (const float*)d_in[12];
  const float* g3   = (const float*)d_in[13];
  const float* be3  = (const float*)d_in[14];
  const float* g4   = (const float*)d_in[15];
  const float* be4  = (const float*)d_in[16];
  const float* W_d2 = (const float*)d_in[17];
  const float* b_d2 = (const float*)d_in[18];
  float* out = (float*)d_out;

  // workspace layout (floats): fc1 16384 | A 204800 | B 409600 | stats | wmat
  float* ws   = (float*)d_ws;
  float* fc1  = ws;             // 12800 == (512,5,5)
  float* A    = ws + 16384;     // max 204800 (layer3 out)
  float* B    = A + 204800;     // max 409600 (layer4 out)
  float* mean = B + 409600;     // 512
  float* rstd = mean + 512;     // 512
  float* wmat = rstd + 512;     // 4761

  fc1_k<<<12800 / 4, 256, 0, stream>>>(W_in, x, b_in, fc1, 12800, 2048);

  // layer1: (512,5,5) -up2+conv-> A (512,10,10)
  conv_k<1><<<(512 * 100 + 255) / 256, 256, 0, stream>>>(fc1, w1, A, 512, 512, 10, 10, 5, 5);
  stats_k<<<512, 256, 0, stream>>>(A, mean, rstd, 100);
  bnrelu_k<<<(51200 + 255) / 256, 256, 0, stream>>>(A, mean, rstd, g1, be1, 100, 51200);

  // layer2 -> B (256,20,20)
  conv_k<1><<<(256 * 400 + 255) / 256, 256, 0, stream>>>(A, w2, B, 512, 256, 20, 20, 10, 10);
  stats_k<<<256, 256, 0, stream>>>(B, mean, rstd, 400);
  bnrelu_k<<<(102400 + 255) / 256, 256, 0, stream>>>(B, mean, rstd, g2, be2, 400, 102400);

  // layer3 -> A (128,40,40)
  conv_k<1><<<(128 * 1600 + 255) / 256, 256, 0, stream>>>(B, w3, A, 256, 128, 40, 40, 20, 20);
  stats_k<<<128, 256, 0, stream>>>(A, mean, rstd, 1600);
  bnrelu_k<<<(204800 + 255) / 256, 256, 0, stream>>>(A, mean, rstd, g3, be3, 1600, 204800);

  // layer4 -> B (64,80,80)
  conv_k<1><<<(64 * 6400 + 255) / 256, 256, 0, stream>>>(A, w4, B, 128, 64, 80, 80, 40, 40);
  stats_k<<<64, 256, 0, stream>>>(B, mean, rstd, 6400);
  bnrelu_k<<<(409600 + 255) / 256, 256, 0, stream>>>(B, mean, rstd, g4, be4, 6400, 409600);

  // layer5: conv (no upsample) -> A (1,80,80), then tanh; A is free (layer3 done)
  conv_k<0><<<(6400 + 255) / 256, 256, 0, stream>>>(B, w5, A, 64, 1, 80, 80, 80, 80);
  tanh_k<<<(6400 + 255) / 256, 256, 0, stream>>>(A, 6400);

  // fc2 -> coupling matrix w (69,69)
  fc2_k<<<4761, 256, 0, stream>>>(W_d2, A, b_d2, wmat, 6400);

  // the serial spiking recurrence: 99800 steps, rows -> out
  scan_k<<<1, 320, 0, stream>>>(wmat, strt + 199 * 69, out, 99800);
}